// Round 14
// baseline (884.822 us; speedup 1.0000x reference)
//
#include <hip/hip_runtime.h>

#define HW 65536

// ---- ws layout (float offsets): weights first (shared by both paths) ----
constexpr int P_K3  = 0;                 // 2048: softmax(scales2) fp32 scratch
constexpr int P_K4  = 2048;              // 256
constexpr int P_S1  = 2304;              // 4
constexpr int P_BNS = 2308;              // 16
constexpr int P_BNB = 2324;              // 16
constexpr int P_WRI = 2340;              // 1024
constexpr int P_WR0 = 3364;              // 128 u32
constexpr int P_WR1 = 3492;              // 1152 u32
constexpr int P_WR2 = 4644;              // 3200 u32
constexpr int P_WR3 = 7844;              // 6272 u32
constexpr int P_WRB = 14116;             // 2304 fp32
constexpr int P_K3U = 16420;             // 512 u32
constexpr int P_K3V = 16932;             // 512 u32
constexpr int OFF_X  = 32768;            // xT 4.19M floats (comb reuses this in fused mode)
constexpr int OFF_CT = 32768 + 4194304;  // cT buffers
constexpr int CTSZ   = 4194304;
// fused:  cT[d] = OFF_CT + d*CTSZ (d=0..3); comb = OFF_X;  need = OFF_CT + 4*CTSZ floats
// seq  :  cT = OFF_CT; maxb = OFF_CT+CTSZ; sumb = OFF_CT+2*CTSZ (67.2 MB, known-good)

typedef _Float16 hv2 __attribute__((ext_vector_type(2)));

__device__ __forceinline__ int h2i(hv2 v) { return __builtin_bit_cast(int, v); }
__device__ __forceinline__ hv2 i2h(int v) { return __builtin_bit_cast(hv2, v); }

__device__ __forceinline__ hv2 pkrtz(float a, float b) {
  return __builtin_bit_cast(hv2, __builtin_amdgcn_cvt_pkrtz(a, b));
}

__device__ __forceinline__ hv2 pk_fma_n(hv2 a, hv2 b, hv2 c) {
#if __has_builtin(__builtin_elementwise_fma)
  return __builtin_elementwise_fma(a, b, c);
#else
  return a * b + c;
#endif
}

__device__ __forceinline__ hv2 pkmin(hv2 a, hv2 b) {
  hv2 d; asm("v_pk_min_f16 %0, %1, %2" : "=v"(d) : "v"(a), "v"(b)); return d;
}
__device__ __forceinline__ hv2 pkmax(hv2 a, hv2 b) {
  hv2 d; asm("v_pk_max_f16 %0, %1, %2" : "=v"(d) : "v"(a), "v"(b)); return d;
}
__device__ __forceinline__ hv2 pkmul(hv2 a, hv2 b) {
  hv2 d; asm("v_pk_mul_f16 %0, %1, %2" : "=v"(d) : "v"(a), "v"(b)); return d;
}
__device__ __forceinline__ hv2 pkfma(hv2 a, hv2 b, hv2 c) {
  hv2 d; asm("v_pk_fma_f16 %0, %1, %2, %3" : "=v"(d) : "v"(a), "v"(b), "v"(c)); return d;
}

__device__ __forceinline__ hv2 sel32(bool c, hv2 a, hv2 b) {
  return i2h(c ? h2i(a) : h2i(b));
}

template <int LMASK>
__device__ __forceinline__ int lane_xor_i(int x) {
  if constexpr (LMASK < 32) {
    return __builtin_amdgcn_ds_swizzle(x, (LMASK << 10) | 0x1F);
  } else {
    return __shfl_xor(x, LMASK, 64);
  }
}

__device__ __forceinline__ float sigmoid_fast(float x) {
  return __fdividef(1.0f, 1.0f + __expf(-x));
}

// ---------------- prep ----------------
__global__ void k_prep(const float* __restrict__ w_in, const float* __restrict__ w_c0,
                       const float* __restrict__ w_c1, const float* __restrict__ w_c2,
                       const float* __restrict__ w_c3, const float* __restrict__ w_base,
                       const float* __restrict__ scales1, const float* __restrict__ scales2,
                       const float* __restrict__ scales3, const float* __restrict__ bn_gamma,
                       const float* __restrict__ bn_beta, const float* __restrict__ bn_mean,
                       const float* __restrict__ bn_var, float* __restrict__ ws) {
  int tid = threadIdx.x;  // 256
  {
    const float* srow = scales2 + tid * 8;
    float v[8]; float mx = -1e30f;
    for (int j = 0; j < 8; j++) { v[j] = srow[j]; mx = fmaxf(mx, v[j]); }
    float s = 0.f;
    for (int j = 0; j < 8; j++) { v[j] = __expf(v[j] - mx); s += v[j]; }
    float inv = 1.0f / s;
    for (int j = 0; j < 8; j++) ws[P_K3 + tid * 8 + j] = v[j] * inv;
  }
  if (tid < 16) {
    const float* srow = scales3 + tid * 16;
    float v[16]; float mx = -1e30f;
    for (int e = 0; e < 16; e++) { v[e] = srow[e]; mx = fmaxf(mx, v[e]); }
    float s = 0.f;
    for (int e = 0; e < 16; e++) { v[e] = __expf(v[e] - mx); s += v[e]; }
    float inv = 1.0f / s;
    for (int e = 0; e < 16; e++) ws[P_K4 + tid * 16 + e] = v[e] * inv;
  }
  if (tid == 0) {
    float v[4]; float mx = -1e30f;
    for (int i = 0; i < 4; i++) { v[i] = scales1[i]; mx = fmaxf(mx, v[i]); }
    float s = 0.f;
    for (int i = 0; i < 4; i++) { v[i] = __expf(v[i] - mx); s += v[i]; }
    for (int i = 0; i < 4; i++) ws[P_S1 + i] = v[i] / s;
  }
  if (tid < 16) {
    float rs = rsqrtf(bn_var[tid] + 1e-5f);
    float sc = bn_gamma[tid] * rs;
    ws[P_BNS + tid] = sc;
    ws[P_BNB + tid] = bn_beta[tid] - bn_mean[tid] * sc;
  }
  for (int i = tid; i < 1024; i += 256) { int ci = i >> 4, co = i & 15; ws[P_WRI + i] = w_in[co * 64 + ci]; }
  {
    uint32_t* w0 = (uint32_t*)(ws + P_WR0);
    for (int i = tid; i < 128; i += 256) {
      int cp = i & 7, ci = i >> 3;
      hv2 wv;
      wv.x = (_Float16)w_c0[(2 * cp) * 16 + ci];
      wv.y = (_Float16)w_c0[(2 * cp + 1) * 16 + ci];
      w0[ci * 8 + cp] = __builtin_bit_cast(uint32_t, wv);
    }
    uint32_t* w1 = (uint32_t*)(ws + P_WR1);
    for (int i = tid; i < 1152; i += 256) {
      int cp = i & 7; int r = i >> 3; int kw = r % 3; r /= 3; int kh = r % 3; int ci = r / 3;
      hv2 wv;
      wv.x = (_Float16)w_c1[((2 * cp) * 16 + ci) * 9 + kh * 3 + kw];
      wv.y = (_Float16)w_c1[((2 * cp + 1) * 16 + ci) * 9 + kh * 3 + kw];
      w1[((ci * 3 + kh) * 3 + kw) * 8 + cp] = __builtin_bit_cast(uint32_t, wv);
    }
    uint32_t* w2 = (uint32_t*)(ws + P_WR2);
    for (int i = tid; i < 3200; i += 256) {
      int cp = i & 7; int r = i >> 3; int kw = r % 5; r /= 5; int kh = r % 5; int ci = r / 5;
      hv2 wv;
      wv.x = (_Float16)w_c2[((2 * cp) * 16 + ci) * 25 + kh * 5 + kw];
      wv.y = (_Float16)w_c2[((2 * cp + 1) * 16 + ci) * 25 + kh * 5 + kw];
      w2[((ci * 5 + kh) * 5 + kw) * 8 + cp] = __builtin_bit_cast(uint32_t, wv);
    }
    uint32_t* w3 = (uint32_t*)(ws + P_WR3);
    for (int i = tid; i < 6272; i += 256) {
      int cp = i & 7; int r = i >> 3; int kw = r % 7; r /= 7; int kh = r % 7; int ci = r / 7;
      hv2 wv;
      wv.x = (_Float16)w_c3[((2 * cp) * 16 + ci) * 49 + kh * 7 + kw];
      wv.y = (_Float16)w_c3[((2 * cp + 1) * 16 + ci) * 49 + kh * 7 + kw];
      w3[((ci * 7 + kh) * 7 + kw) * 8 + cp] = __builtin_bit_cast(uint32_t, wv);
    }
  }
  for (int i = tid; i < 2304; i += 256) {
    int co = i & 15; int r = i >> 4; int kh = r % 3; r /= 3; int kw = r % 3; int g = r / 3;
    ws[P_WRB + i] = w_base[((co * 16 + g) * 3 + kh) * 3 + kw];
  }
  __syncthreads();
  uint32_t* k3u = (uint32_t*)(ws + P_K3U);
  uint32_t* k3v = (uint32_t*)(ws + P_K3V);
  for (int i = tid; i < 512; i += 256) {
    int g = i >> 5, p = (i >> 2) & 7, j = i & 3;
    const float* r0 = ws + P_K3 + g * 128 + (2 * p) * 8;
    const float* r1 = ws + P_K3 + g * 128 + (2 * p + 1) * 8;
    hv2 wu, wv;
    wu.x = (_Float16)((r0[j] + r0[j + 4]) * 0.5f);
    wu.y = (_Float16)((r1[j] + r1[j + 4]) * 0.5f);
    wv.x = (_Float16)((r0[j] - r0[j + 4]) * 0.5f);
    wv.y = (_Float16)((r1[j] - r1[j + 4]) * 0.5f);
    k3u[i] = __builtin_bit_cast(uint32_t, wu);
    k3v[i] = __builtin_bit_cast(uint32_t, wv);
  }
}

// ---------------- 1x1 conv 64->16, writes TRANSPOSED xT[b][ci][w][h] ----------------
__global__ __launch_bounds__(256) void k_in(const float* __restrict__ cen,
                                            const float* __restrict__ b_in,
                                            const float* __restrict__ ws,
                                            float* __restrict__ xT) {
  __shared__ float ldst[16 * 16 * 17];
  int tid = threadIdx.x;
  int b = blockIdx.z;
  int hbase = blockIdx.y * 16, wbase = blockIdx.x * 16;
  int ty = tid >> 4, tx = tid & 15;
  const float* wri = ws + P_WRI;
  float acc[16];
#pragma unroll
  for (int co = 0; co < 16; co++) acc[co] = b_in[co];
  const float* cp = cen + b * 64 * HW + (hbase + ty) * 256 + wbase + tx;
#pragma unroll 4
  for (int ci = 0; ci < 64; ci++) {
    float v = cp[ci * HW];
#pragma unroll
    for (int co = 0; co < 16; co++) acc[co] = fmaf(wri[ci * 16 + co], v, acc[co]);
  }
#pragma unroll
  for (int co = 0; co < 16; co++) ldst[(co * 16 + tx) * 17 + ty] = acc[co];
  __syncthreads();
  int wy = tid >> 4, hx = tid & 15;
#pragma unroll
  for (int ci = 0; ci < 16; ci++) {
    xT[((b * 16 + ci) << 16) + (wbase + wy) * 256 + hbase + hx] =
        ldst[(ci * 16 + wy) * 17 + hx];
  }
}

// ---------------- branch conv: direct per-kh offset loads ----------------
template <int KS, bool SAFE>
__device__ __forceinline__ void conv_body(const float* __restrict__ xb,
                                          const uint32_t* __restrict__ wrh,
                                          int w, int hbase, int lane, hv2 acc[8]) {
  constexpr int P = KS / 2;
#pragma unroll 2
  for (int ci = 0; ci < 16; ci++) {
#pragma unroll
    for (int kw = 0; kw < KS; kw++) {
      const int wc = w + kw - P;
      if (KS > 1 && (unsigned)wc >= 256u) continue;
      const float* col = xb + (ci << 16) + (wc << 8);
      const int hb = hbase + lane - P;
#pragma unroll
      for (int kh = 0; kh < KS; kh++) {
        float tv;
        if constexpr (SAFE) {
          tv = col[hb + kh];
        } else {
          const int h = hb + kh;
          tv = ((unsigned)h < 256u) ? col[h] : 0.0f;
        }
        const hv2 tp = pkrtz(tv, tv);
        const uint32_t* wp = wrh + ((ci * KS + kh) * KS + kw) * 8;
#pragma unroll
        for (int cp = 0; cp < 8; cp++)
          acc[cp] = pk_fma_n(i2h((int)wp[cp]), tp, acc[cp]);
      }
    }
  }
}

template <int KS>
__global__ __launch_bounds__(256) void k_conv(const float* __restrict__ xT,
                                              const float* __restrict__ bias,
                                              const uint32_t* __restrict__ wrh,
                                              float* __restrict__ cT) {
  const int tid = threadIdx.x;
  const int lane = tid & 63;
  const int wv = (blockIdx.x << 2) + (tid >> 6);
  const int hseg = wv & 3;
  const int w = (wv >> 2) & 255;
  const int b = wv >> 10;
  const int hbase = hseg << 6;
  const float* xb = xT + ((b * 16) << 16);

  hv2 acc[8];
#pragma unroll
  for (int cp = 0; cp < 8; cp++) {
    hv2 bv;
    bv.x = (_Float16)bias[2 * cp];
    bv.y = (_Float16)bias[2 * cp + 1];
    acc[cp] = bv;
  }

  if (KS == 1 || (hseg != 0 && hseg != 3)) {
    conv_body<KS, true>(xb, wrh, w, hbase, lane, acc);
  } else {
    conv_body<KS, false>(xb, wrh, w, hbase, lane, acc);
  }

  float* o = cT + ((b * 16) << 16) + (w << 8) + hbase + lane;
#pragma unroll
  for (int cp = 0; cp < 8; cp++) {
    o[(2 * cp) << 16] = (float)acc[cp].x;
    o[(2 * cp + 1) << 16] = (float)acc[cp].y;
  }
}

// ---------------- packed-fp16 bitonic sort of 256 values ----------------
__device__ __forceinline__ void ce_pair_h(hv2& a, hv2& b, bool up) {
  hv2 lo = pkmin(a, b);
  hv2 hi = pkmax(a, b);
  a = sel32(up, lo, hi);
  b = sel32(up, hi, lo);
}

template <int SIZE, int DIST>
__device__ __forceinline__ void stage_x_h(hv2 v[4], int i0) {
  const bool keepmin = (((i0 & DIST) == 0) == ((i0 & SIZE) == 0));
#pragma unroll
  for (int r = 0; r < 4; r++) {
    hv2 pv = i2h(lane_xor_i<(DIST >> 2)>(h2i(v[r])));
    v[r] = sel32(keepmin, pkmin(v[r], pv), pkmax(v[r], pv));
  }
}

template <int SIZE>
__device__ __forceinline__ void stage_d21_h(hv2 v[4], int i0) {
  bool up = ((i0 & SIZE) == 0);
  ce_pair_h(v[0], v[2], up); ce_pair_h(v[1], v[3], up);
  ce_pair_h(v[0], v[1], up); ce_pair_h(v[2], v[3], up);
}

__device__ __forceinline__ void sort256h(hv2 v[4], int lane) {
  int i0 = lane << 2;
  ce_pair_h(v[0], v[1], true); ce_pair_h(v[2], v[3], false);
  stage_d21_h<4>(v, i0);
  stage_x_h<8, 4>(v, i0); stage_d21_h<8>(v, i0);
  stage_x_h<16, 8>(v, i0); stage_x_h<16, 4>(v, i0); stage_d21_h<16>(v, i0);
  stage_x_h<32, 16>(v, i0); stage_x_h<32, 8>(v, i0); stage_x_h<32, 4>(v, i0); stage_d21_h<32>(v, i0);
  stage_x_h<64, 32>(v, i0); stage_x_h<64, 16>(v, i0); stage_x_h<64, 8>(v, i0); stage_x_h<64, 4>(v, i0); stage_d21_h<64>(v, i0);
  stage_x_h<128, 64>(v, i0); stage_x_h<128, 32>(v, i0); stage_x_h<128, 16>(v, i0); stage_x_h<128, 8>(v, i0); stage_x_h<128, 4>(v, i0); stage_d21_h<128>(v, i0);
  stage_x_h<256, 128>(v, i0); stage_x_h<256, 64>(v, i0); stage_x_h<256, 32>(v, i0); stage_x_h<256, 16>(v, i0); stage_x_h<256, 8>(v, i0); stage_x_h<256, 4>(v, i0); stage_d21_h<256>(v, i0);
}

// ---------------- one branch: diff/k3(u,v)/mul/sort/silu/k4 -> out[4] ----------------
template <int DIL>
__device__ __forceinline__ void branch_one(const float* __restrict__ base,
                                           const float* __restrict__ ws,
                                           int g, int w, int lane, float out[4]) {
  float vals[3][3][4];
#pragma unroll
  for (int wi = 0; wi < 3; ++wi) {
    const int wc = w + (wi - 1) * DIL;
    const bool wok = ((unsigned)wc < 256u);
    const float* col = base + (wok ? wc : 0) * 256;
#pragma unroll
    for (int si = 0; si < 3; ++si) {
#pragma unroll
      for (int r = 0; r < 4; ++r) {
        const int h = lane + (r << 6) + (si - 1) * DIL;
        const bool ok = wok && ((unsigned)h < 256u);
        vals[wi][si][r] = ok ? col[h] : 0.0f;
      }
    }
  }
  hv2 uh[4][4], vh[4][4];
#pragma unroll
  for (int r = 0; r < 4; ++r) {
    const float c0 = vals[1][1][r];
    float d0 = c0 - vals[0][0][r];
    float d1 = c0 - vals[1][0][r];
    float d2 = c0 - vals[2][0][r];
    float d3 = c0 - vals[0][1][r];
    float d4 = c0 - vals[2][2][r];
    float d5 = c0 - vals[1][2][r];
    float d6 = c0 - vals[0][2][r];
    float d7 = c0 - vals[2][1][r];
    uh[0][r] = pkrtz(d0 + d4, d0 + d4);
    uh[1][r] = pkrtz(d1 + d5, d1 + d5);
    uh[2][r] = pkrtz(d2 + d6, d2 + d6);
    uh[3][r] = pkrtz(d3 + d7, d3 + d7);
    vh[0][r] = pkrtz(d0 - d4, d0 - d4);
    vh[1][r] = pkrtz(d1 - d5, d1 - d5);
    vh[2][r] = pkrtz(d2 - d6, d2 - d6);
    vh[3][r] = pkrtz(d3 - d7, d3 - d7);
  }
  out[0] = out[1] = out[2] = out[3] = 0.f;
  const uint32_t* k3u = (const uint32_t*)(ws + P_K3U) + g * 32;
  const uint32_t* k3v = (const uint32_t*)(ws + P_K3V) + g * 32;
  const float* k4p = ws + P_K4 + g * 16;
#pragma unroll 1
  for (int p = 0; p < 8; ++p) {
    hv2 t[4];
    hv2 wu[4], wvv[4];
#pragma unroll
    for (int j = 0; j < 4; ++j) {
      wu[j]  = i2h((int)k3u[p * 4 + j]);
      wvv[j] = i2h((int)k3v[p * 4 + j]);
    }
#pragma unroll
    for (int r = 0; r < 4; ++r) {
      hv2 s = pkmul(wu[0], uh[0][r]);
      s = pkfma(wu[1], uh[1][r], s);
      s = pkfma(wu[2], uh[2][r], s);
      s = pkfma(wu[3], uh[3][r], s);
      hv2 d = pkmul(wvv[0], vh[0][r]);
      d = pkfma(wvv[1], vh[1][r], d);
      d = pkfma(wvv[2], vh[2][r], d);
      d = pkfma(wvv[3], vh[3][r], d);
      t[r] = pkmul(s + d, s - d);
    }
    sort256h(t, lane);
    const float k4a = k4p[2 * p], k4b = k4p[2 * p + 1];
#pragma unroll
    for (int r = 0; r < 4; ++r) {
      const float va = (float)t[r].x;
      const float vb = (float)t[r].y;
      out[r] = fmaf(k4a, va * sigmoid_fast(va), out[r]);
      out[r] = fmaf(k4b, vb * sigmoid_fast(vb), out[r]);
    }
  }
}

// ---------------- fused: all 4 dilations, register max/sum, write comb ----------------
__global__ __launch_bounds__(256) void k_branch4(const float* __restrict__ cT,
                                                 const float* __restrict__ ws,
                                                 float* __restrict__ comb) {
  const int tid = threadIdx.x;
  const int lane = tid & 63;
  const int wid = __builtin_amdgcn_readfirstlane(tid >> 6);
  const int wv = (blockIdx.x << 2) + wid;
  const int w = wv & 255;
  const int g = (wv >> 8) & 15;
  const int b = wv >> 12;
  const int boff = (b * 16 + g) << 16;

  float out[4], mx[4], sm[4];
  branch_one<1>(cT + 0 * CTSZ + boff, ws, g, w, lane, out);
#pragma unroll
  for (int r = 0; r < 4; ++r) { mx[r] = out[r]; sm[r] = out[r]; }
  branch_one<3>(cT + 1 * CTSZ + boff, ws, g, w, lane, out);
#pragma unroll
  for (int r = 0; r < 4; ++r) { mx[r] = fmaxf(mx[r], out[r]); sm[r] += out[r]; }
  branch_one<5>(cT + 2 * CTSZ + boff, ws, g, w, lane, out);
#pragma unroll
  for (int r = 0; r < 4; ++r) { mx[r] = fmaxf(mx[r], out[r]); sm[r] += out[r]; }
  branch_one<7>(cT + 3 * CTSZ + boff, ws, g, w, lane, out);
#pragma unroll
  for (int r = 0; r < 4; ++r) { mx[r] = fmaxf(mx[r], out[r]); sm[r] += out[r]; }

  const int obase = (((b * 16 + g) << 8) + w) * 256 + (lane << 2);
  float4 o4;
  o4.x = fmaf(0.25f, sm[0], mx[0]);
  o4.y = fmaf(0.25f, sm[1], mx[1]);
  o4.z = fmaf(0.25f, sm[2], mx[2]);
  o4.w = fmaf(0.25f, sm[3], mx[3]);
  *(float4*)(comb + obase) = o4;
}

// ---------------- sequential fallback: one branch with RMW max/sum ----------------
template <int DIL>
__global__ __launch_bounds__(256) void k_branch(const float* __restrict__ cT,
                                                const float* __restrict__ ws,
                                                float* __restrict__ maxb,
                                                float* __restrict__ sumb,
                                                int initFlag) {
  const int tid = threadIdx.x;
  const int lane = tid & 63;
  const int wid = __builtin_amdgcn_readfirstlane(tid >> 6);
  const int wv = (blockIdx.x << 2) + wid;
  const int w = wv & 255;
  const int g = (wv >> 8) & 15;
  const int b = wv >> 12;

  float out[4];
  branch_one<DIL>(cT + ((b * 16 + g) << 16), ws, g, w, lane, out);

  const int obase = (((b * 16 + g) << 8) + w) * 256 + (lane << 2);
  float4 o4 = make_float4(out[0], out[1], out[2], out[3]);
  float4* mp = (float4*)(maxb + obase);
  float4* sp = (float4*)(sumb + obase);
  if (initFlag) {
    *mp = o4;
    *sp = o4;
  } else {
    float4 m = *mp;
    m.x = fmaxf(m.x, o4.x); m.y = fmaxf(m.y, o4.y);
    m.z = fmaxf(m.z, o4.z); m.w = fmaxf(m.w, o4.w);
    *mp = m;
    float4 s = *sp;
    s.x += o4.x; s.y += o4.y; s.z += o4.z; s.w += o4.w;
    *sp = s;
  }
}

// ---------------- combine + 3x3 conv + BN + SiLU + 1x1 + sigmoid + GATE ----------------
// combMode=1: `a` already holds max+0.25*sum; combMode=0: a=maxb, sb=sumb
__global__ __launch_bounds__(256) void k_tail(const float* __restrict__ a,
                                              const float* __restrict__ sb,
                                              const float* __restrict__ ws,
                                              const float* __restrict__ cen,
                                              const float* __restrict__ mas,
                                              const float* __restrict__ w_out,
                                              const float* __restrict__ b_out,
                                              float* __restrict__ out,
                                              int combMode) {
  __shared__ float lds[16 * 18 * 18];
  __shared__ float ldsf[256];
  int tid = threadIdx.x;
  int b = blockIdx.z;
  int wbase = blockIdx.x * 16, hbase = blockIdx.y * 16;
  const float* mb = a + (b * 16) * HW;
  const float* sbb = sb + (b * 16) * HW;
  for (int i = tid; i < 16 * 18 * 18; i += 256) {
    int g = i / 324; int r = i % 324; int xx = r / 18, yy = r % 18;
    int wq = wbase + xx - 1, hq = hbase + yy - 1;
    float v = 0.0f;
    if (wq >= 0 && wq < 256 && hq >= 0 && hq < 256) {
      int idx = g * HW + wq * 256 + hq;
      v = mb[idx];
      if (!combMode) v += 0.25f * sbb[idx];
    }
    lds[i] = v;
  }
  __syncthreads();
  int xw = tid >> 4, yh = tid & 15;
  float acc[16] = {0.f, 0.f, 0.f, 0.f, 0.f, 0.f, 0.f, 0.f,
                   0.f, 0.f, 0.f, 0.f, 0.f, 0.f, 0.f, 0.f};
  for (int g = 0; g < 16; g++) {
#pragma unroll
    for (int kw = 0; kw < 3; kw++) {
#pragma unroll
      for (int kh = 0; kh < 3; kh++) {
        float v = lds[g * 324 + (xw + kw) * 18 + (yh + kh)];
        const float* wp = ws + P_WRB + ((g * 3 + kw) * 3 + kh) * 16;
#pragma unroll
        for (int co = 0; co < 16; co++) acc[co] = fmaf(wp[co], v, acc[co]);
      }
    }
  }
  float mo = b_out[0];
#pragma unroll
  for (int co = 0; co < 16; co++) {
    float z = acc[co] * ws[P_BNS + co] + ws[P_BNB + co];
    float sl = z * sigmoid_fast(z);
    mo = fmaf(w_out[co], sl, mo);
  }
  float mk = sigmoid_fast(mo);
  ldsf[yh * 16 + xw] = mk;
  __syncthreads();
  {
    int yy = tid >> 4, xx = tid & 15;
    float mkv = ldsf[yy * 16 + xx];
    float m = sigmoid_fast(mas[b * HW + (hbase + yy) * 256 + wbase + xx]);
    float s0 = ws[P_S1], s1 = ws[P_S1 + 1], s2 = ws[P_S1 + 2], s3 = ws[P_S1 + 3];
    float f = mkv * m * s0 + m * s1 + s2 * mkv + s3;
    ldsf[yy * 16 + xx] = f;
  }
  __syncthreads();
  const float* cb = cen + b * 64 * HW;
  float* ob = out + b * 64 * HW;
#pragma unroll 4
  for (int it = 0; it < 16; ++it) {
    int flat = it * 256 + tid;
    int ci = flat >> 6;
    int rr = flat & 63;
    int yy = rr >> 2, wq = rr & 3;
    const float* fr = &ldsf[yy * 16 + wq * 4];
    float4 f4 = make_float4(fr[0], fr[1], fr[2], fr[3]);
    int addr = ci * HW + (hbase + yy) * 256 + wbase + wq * 4;
    const float4 c4 = *(const float4*)(cb + addr);
    float4 o4;
    o4.x = c4.x * f4.x; o4.y = c4.y * f4.y; o4.z = c4.z * f4.z; o4.w = c4.w * f4.w;
    *(float4*)(ob + addr) = o4;
  }
}

extern "C" void kernel_launch(void* const* d_in, const int* in_sizes, int n_in,
                              void* d_out, int out_size, void* d_ws, size_t ws_size,
                              hipStream_t stream) {
  (void)in_sizes; (void)n_in; (void)out_size;
  const float* cen = (const float*)d_in[0];
  const float* mas = (const float*)d_in[1];
  const float* w_in = (const float*)d_in[2];
  const float* b_in = (const float*)d_in[3];
  const float* w_c0 = (const float*)d_in[4];
  const float* b_c0 = (const float*)d_in[5];
  const float* w_c1 = (const float*)d_in[6];
  const float* b_c1 = (const float*)d_in[7];
  const float* w_c2 = (const float*)d_in[8];
  const float* b_c2 = (const float*)d_in[9];
  const float* w_c3 = (const float*)d_in[10];
  const float* b_c3 = (const float*)d_in[11];
  const float* scales1 = (const float*)d_in[12];
  const float* scales2 = (const float*)d_in[13];
  const float* scales3 = (const float*)d_in[14];
  const float* w_base = (const float*)d_in[15];
  const float* bn_gamma = (const float*)d_in[16];
  const float* bn_beta = (const float*)d_in[17];
  const float* bn_mean = (const float*)d_in[18];
  const float* bn_var = (const float*)d_in[19];
  const float* w_out = (const float*)d_in[20];
  const float* b_out = (const float*)d_in[21];
  float* ws = (float*)d_ws;
  float* out = (float*)d_out;

  float* xT = ws + OFF_X;
  float* cT = ws + OFF_CT;

  const size_t needFused = (size_t)(OFF_CT + 4 * CTSZ) * 4;  // 84.0 MB
  const bool fused = ws_size >= needFused;

  k_prep<<<1, 256, 0, stream>>>(w_in, w_c0, w_c1, w_c2, w_c3, w_base, scales1, scales2,
                                scales3, bn_gamma, bn_beta, bn_mean, bn_var, ws);
  k_in<<<dim3(16, 16, 4), 256, 0, stream>>>(cen, b_in, ws, xT);

  if (fused) {
    k_conv<1><<<1024, 256, 0, stream>>>(xT, b_c0, (const uint32_t*)(ws + P_WR0), cT + 0 * CTSZ);
    k_conv<3><<<1024, 256, 0, stream>>>(xT, b_c1, (const uint32_t*)(ws + P_WR1), cT + 1 * CTSZ);
    k_conv<5><<<1024, 256, 0, stream>>>(xT, b_c2, (const uint32_t*)(ws + P_WR2), cT + 2 * CTSZ);
    k_conv<7><<<1024, 256, 0, stream>>>(xT, b_c3, (const uint32_t*)(ws + P_WR3), cT + 3 * CTSZ);
    float* comb = xT;  // xT dead after the 4 convs
    k_branch4<<<4096, 256, 0, stream>>>(cT, ws, comb);
    k_tail<<<dim3(16, 16, 4), 256, 0, stream>>>(comb, comb, ws, cen, mas, w_out, b_out, out, 1);
  } else {
    float* maxb = cT + CTSZ;
    float* sumb = cT + 2 * CTSZ;
    k_conv<1><<<1024, 256, 0, stream>>>(xT, b_c0, (const uint32_t*)(ws + P_WR0), cT);
    k_branch<1><<<4096, 256, 0, stream>>>(cT, ws, maxb, sumb, 1);
    k_conv<3><<<1024, 256, 0, stream>>>(xT, b_c1, (const uint32_t*)(ws + P_WR1), cT);
    k_branch<3><<<4096, 256, 0, stream>>>(cT, ws, maxb, sumb, 0);
    k_conv<5><<<1024, 256, 0, stream>>>(xT, b_c2, (const uint32_t*)(ws + P_WR2), cT);
    k_branch<5><<<4096, 256, 0, stream>>>(cT, ws, maxb, sumb, 0);
    k_conv<7><<<1024, 256, 0, stream>>>(xT, b_c3, (const uint32_t*)(ws + P_WR3), cT);
    k_branch<7><<<4096, 256, 0, stream>>>(cT, ws, maxb, sumb, 0);
    k_tail<<<dim3(16, 16, 4), 256, 0, stream>>>(maxb, sumb, ws, cen, mas, w_out, b_out, out, 0);
  }
}

// Round 15
// 879.713 us; speedup vs baseline: 1.0058x; 1.0058x over previous
//
#include <hip/hip_runtime.h>

#define HW 65536

// ---- ws layout (float offsets): weights first (shared by both paths) ----
constexpr int P_K3  = 0;                 // 2048: softmax(scales2) fp32 scratch
constexpr int P_K4  = 2048;              // 256
constexpr int P_S1  = 2304;              // 4
constexpr int P_BNS = 2308;              // 16
constexpr int P_BNB = 2324;              // 16
constexpr int P_WRI = 2340;              // 1024
constexpr int P_WR0 = 3364;              // 128 u32
constexpr int P_WR1 = 3492;              // 1152 u32
constexpr int P_WR2 = 4644;              // 3200 u32
constexpr int P_WR3 = 7844;              // 6272 u32
constexpr int P_WRB = 14116;             // 2304 fp32
constexpr int P_K3U = 16420;             // 512 u32
constexpr int P_K3V = 16932;             // 512 u32
constexpr int OFF_X  = 32768;            // xT 4.19M floats (comb reuses this in fused mode)
constexpr int OFF_CT = 32768 + 4194304;  // cT buffers
constexpr int CTSZ   = 4194304;
// fused:  cT[d] = OFF_CT + d*CTSZ (d=0..3); comb = OFF_X;  need = OFF_CT + 4*CTSZ floats
// seq  :  cT = OFF_CT; maxb = OFF_CT+CTSZ; sumb = OFF_CT+2*CTSZ (67.2 MB, known-good)

typedef _Float16 hv2 __attribute__((ext_vector_type(2)));

__device__ __forceinline__ int h2i(hv2 v) { return __builtin_bit_cast(int, v); }
__device__ __forceinline__ hv2 i2h(int v) { return __builtin_bit_cast(hv2, v); }

__device__ __forceinline__ hv2 pkrtz(float a, float b) {
  return __builtin_bit_cast(hv2, __builtin_amdgcn_cvt_pkrtz(a, b));
}

__device__ __forceinline__ hv2 pk_fma_n(hv2 a, hv2 b, hv2 c) {
#if __has_builtin(__builtin_elementwise_fma)
  return __builtin_elementwise_fma(a, b, c);
#else
  return a * b + c;
#endif
}

__device__ __forceinline__ hv2 pkmin(hv2 a, hv2 b) {
  hv2 d; asm("v_pk_min_f16 %0, %1, %2" : "=v"(d) : "v"(a), "v"(b)); return d;
}
__device__ __forceinline__ hv2 pkmax(hv2 a, hv2 b) {
  hv2 d; asm("v_pk_max_f16 %0, %1, %2" : "=v"(d) : "v"(a), "v"(b)); return d;
}
__device__ __forceinline__ hv2 pkmul(hv2 a, hv2 b) {
  hv2 d; asm("v_pk_mul_f16 %0, %1, %2" : "=v"(d) : "v"(a), "v"(b)); return d;
}
__device__ __forceinline__ hv2 pkfma(hv2 a, hv2 b, hv2 c) {
  hv2 d; asm("v_pk_fma_f16 %0, %1, %2, %3" : "=v"(d) : "v"(a), "v"(b), "v"(c)); return d;
}

__device__ __forceinline__ hv2 sel32(bool c, hv2 a, hv2 b) {
  return i2h(c ? h2i(a) : h2i(b));
}

template <int LMASK>
__device__ __forceinline__ int lane_xor_i(int x) {
  if constexpr (LMASK < 32) {
    return __builtin_amdgcn_ds_swizzle(x, (LMASK << 10) | 0x1F);
  } else {
    return __shfl_xor(x, LMASK, 64);
  }
}

__device__ __forceinline__ float sigmoid_fast(float x) {
  return __fdividef(1.0f, 1.0f + __expf(-x));
}

// ---------------- prep ----------------
__global__ void k_prep(const float* __restrict__ w_in, const float* __restrict__ w_c0,
                       const float* __restrict__ w_c1, const float* __restrict__ w_c2,
                       const float* __restrict__ w_c3, const float* __restrict__ w_base,
                       const float* __restrict__ scales1, const float* __restrict__ scales2,
                       const float* __restrict__ scales3, const float* __restrict__ bn_gamma,
                       const float* __restrict__ bn_beta, const float* __restrict__ bn_mean,
                       const float* __restrict__ bn_var, float* __restrict__ ws) {
  int tid = threadIdx.x;  // 256
  {
    const float* srow = scales2 + tid * 8;
    float v[8]; float mx = -1e30f;
    for (int j = 0; j < 8; j++) { v[j] = srow[j]; mx = fmaxf(mx, v[j]); }
    float s = 0.f;
    for (int j = 0; j < 8; j++) { v[j] = __expf(v[j] - mx); s += v[j]; }
    float inv = 1.0f / s;
    for (int j = 0; j < 8; j++) ws[P_K3 + tid * 8 + j] = v[j] * inv;
  }
  if (tid < 16) {
    const float* srow = scales3 + tid * 16;
    float v[16]; float mx = -1e30f;
    for (int e = 0; e < 16; e++) { v[e] = srow[e]; mx = fmaxf(mx, v[e]); }
    float s = 0.f;
    for (int e = 0; e < 16; e++) { v[e] = __expf(v[e] - mx); s += v[e]; }
    float inv = 1.0f / s;
    for (int e = 0; e < 16; e++) ws[P_K4 + tid * 16 + e] = v[e] * inv;
  }
  if (tid == 0) {
    float v[4]; float mx = -1e30f;
    for (int i = 0; i < 4; i++) { v[i] = scales1[i]; mx = fmaxf(mx, v[i]); }
    float s = 0.f;
    for (int i = 0; i < 4; i++) { v[i] = __expf(v[i] - mx); s += v[i]; }
    for (int i = 0; i < 4; i++) ws[P_S1 + i] = v[i] / s;
  }
  if (tid < 16) {
    float rs = rsqrtf(bn_var[tid] + 1e-5f);
    float sc = bn_gamma[tid] * rs;
    ws[P_BNS + tid] = sc;
    ws[P_BNB + tid] = bn_beta[tid] - bn_mean[tid] * sc;
  }
  for (int i = tid; i < 1024; i += 256) { int ci = i >> 4, co = i & 15; ws[P_WRI + i] = w_in[co * 64 + ci]; }
  {
    uint32_t* w0 = (uint32_t*)(ws + P_WR0);
    for (int i = tid; i < 128; i += 256) {
      int cp = i & 7, ci = i >> 3;
      hv2 wv;
      wv.x = (_Float16)w_c0[(2 * cp) * 16 + ci];
      wv.y = (_Float16)w_c0[(2 * cp + 1) * 16 + ci];
      w0[ci * 8 + cp] = __builtin_bit_cast(uint32_t, wv);
    }
    uint32_t* w1 = (uint32_t*)(ws + P_WR1);
    for (int i = tid; i < 1152; i += 256) {
      int cp = i & 7; int r = i >> 3; int kw = r % 3; r /= 3; int kh = r % 3; int ci = r / 3;
      hv2 wv;
      wv.x = (_Float16)w_c1[((2 * cp) * 16 + ci) * 9 + kh * 3 + kw];
      wv.y = (_Float16)w_c1[((2 * cp + 1) * 16 + ci) * 9 + kh * 3 + kw];
      w1[((ci * 3 + kh) * 3 + kw) * 8 + cp] = __builtin_bit_cast(uint32_t, wv);
    }
    uint32_t* w2 = (uint32_t*)(ws + P_WR2);
    for (int i = tid; i < 3200; i += 256) {
      int cp = i & 7; int r = i >> 3; int kw = r % 5; r /= 5; int kh = r % 5; int ci = r / 5;
      hv2 wv;
      wv.x = (_Float16)w_c2[((2 * cp) * 16 + ci) * 25 + kh * 5 + kw];
      wv.y = (_Float16)w_c2[((2 * cp + 1) * 16 + ci) * 25 + kh * 5 + kw];
      w2[((ci * 5 + kh) * 5 + kw) * 8 + cp] = __builtin_bit_cast(uint32_t, wv);
    }
    uint32_t* w3 = (uint32_t*)(ws + P_WR3);
    for (int i = tid; i < 6272; i += 256) {
      int cp = i & 7; int r = i >> 3; int kw = r % 7; r /= 7; int kh = r % 7; int ci = r / 7;
      hv2 wv;
      wv.x = (_Float16)w_c3[((2 * cp) * 16 + ci) * 49 + kh * 7 + kw];
      wv.y = (_Float16)w_c3[((2 * cp + 1) * 16 + ci) * 49 + kh * 7 + kw];
      w3[((ci * 7 + kh) * 7 + kw) * 8 + cp] = __builtin_bit_cast(uint32_t, wv);
    }
  }
  for (int i = tid; i < 2304; i += 256) {
    int co = i & 15; int r = i >> 4; int kh = r % 3; r /= 3; int kw = r % 3; int g = r / 3;
    ws[P_WRB + i] = w_base[((co * 16 + g) * 3 + kh) * 3 + kw];
  }
  __syncthreads();
  uint32_t* k3u = (uint32_t*)(ws + P_K3U);
  uint32_t* k3v = (uint32_t*)(ws + P_K3V);
  for (int i = tid; i < 512; i += 256) {
    int g = i >> 5, p = (i >> 2) & 7, j = i & 3;
    const float* r0 = ws + P_K3 + g * 128 + (2 * p) * 8;
    const float* r1 = ws + P_K3 + g * 128 + (2 * p + 1) * 8;
    hv2 wu, wv;
    wu.x = (_Float16)((r0[j] + r0[j + 4]) * 0.5f);
    wu.y = (_Float16)((r1[j] + r1[j + 4]) * 0.5f);
    wv.x = (_Float16)((r0[j] - r0[j + 4]) * 0.5f);
    wv.y = (_Float16)((r1[j] - r1[j + 4]) * 0.5f);
    k3u[i] = __builtin_bit_cast(uint32_t, wu);
    k3v[i] = __builtin_bit_cast(uint32_t, wv);
  }
}

// ---------------- 1x1 conv 64->16, writes TRANSPOSED xT[b][ci][w][h] ----------------
__global__ __launch_bounds__(256) void k_in(const float* __restrict__ cen,
                                            const float* __restrict__ b_in,
                                            const float* __restrict__ ws,
                                            float* __restrict__ xT) {
  __shared__ float ldst[16 * 16 * 17];
  int tid = threadIdx.x;
  int b = blockIdx.z;
  int hbase = blockIdx.y * 16, wbase = blockIdx.x * 16;
  int ty = tid >> 4, tx = tid & 15;
  const float* wri = ws + P_WRI;
  float acc[16];
#pragma unroll
  for (int co = 0; co < 16; co++) acc[co] = b_in[co];
  const float* cp = cen + b * 64 * HW + (hbase + ty) * 256 + wbase + tx;
#pragma unroll 4
  for (int ci = 0; ci < 64; ci++) {
    float v = cp[ci * HW];
#pragma unroll
    for (int co = 0; co < 16; co++) acc[co] = fmaf(wri[ci * 16 + co], v, acc[co]);
  }
#pragma unroll
  for (int co = 0; co < 16; co++) ldst[(co * 16 + tx) * 17 + ty] = acc[co];
  __syncthreads();
  int wy = tid >> 4, hx = tid & 15;
#pragma unroll
  for (int ci = 0; ci < 16; ci++) {
    xT[((b * 16 + ci) << 16) + (wbase + wy) * 256 + hbase + hx] =
        ldst[(ci * 16 + wy) * 17 + hx];
  }
}

// ---------------- branch conv: direct per-kh offset loads ----------------
template <int KS, bool SAFE>
__device__ __forceinline__ void conv_body(const float* __restrict__ xb,
                                          const uint32_t* __restrict__ wrh,
                                          int w, int hbase, int lane, hv2 acc[8]) {
  constexpr int P = KS / 2;
#pragma unroll 2
  for (int ci = 0; ci < 16; ci++) {
#pragma unroll
    for (int kw = 0; kw < KS; kw++) {
      const int wc = w + kw - P;
      if (KS > 1 && (unsigned)wc >= 256u) continue;
      const float* col = xb + (ci << 16) + (wc << 8);
      const int hb = hbase + lane - P;
#pragma unroll
      for (int kh = 0; kh < KS; kh++) {
        float tv;
        if constexpr (SAFE) {
          tv = col[hb + kh];
        } else {
          const int h = hb + kh;
          tv = ((unsigned)h < 256u) ? col[h] : 0.0f;
        }
        const hv2 tp = pkrtz(tv, tv);
        const uint32_t* wp = wrh + ((ci * KS + kh) * KS + kw) * 8;
#pragma unroll
        for (int cp = 0; cp < 8; cp++)
          acc[cp] = pk_fma_n(i2h((int)wp[cp]), tp, acc[cp]);
      }
    }
  }
}

template <int KS>
__global__ __launch_bounds__(256) void k_conv(const float* __restrict__ xT,
                                              const float* __restrict__ bias,
                                              const uint32_t* __restrict__ wrh,
                                              float* __restrict__ cT) {
  const int tid = threadIdx.x;
  const int lane = tid & 63;
  const int wv = (blockIdx.x << 2) + (tid >> 6);
  const int hseg = wv & 3;
  const int w = (wv >> 2) & 255;
  const int b = wv >> 10;
  const int hbase = hseg << 6;
  const float* xb = xT + ((b * 16) << 16);

  hv2 acc[8];
#pragma unroll
  for (int cp = 0; cp < 8; cp++) {
    hv2 bv;
    bv.x = (_Float16)bias[2 * cp];
    bv.y = (_Float16)bias[2 * cp + 1];
    acc[cp] = bv;
  }

  if (KS == 1 || (hseg != 0 && hseg != 3)) {
    conv_body<KS, true>(xb, wrh, w, hbase, lane, acc);
  } else {
    conv_body<KS, false>(xb, wrh, w, hbase, lane, acc);
  }

  float* o = cT + ((b * 16) << 16) + (w << 8) + hbase + lane;
#pragma unroll
  for (int cp = 0; cp < 8; cp++) {
    o[(2 * cp) << 16] = (float)acc[cp].x;
    o[(2 * cp + 1) << 16] = (float)acc[cp].y;
  }
}

// ---------------- packed-fp16 bitonic sort of 256 values ----------------
__device__ __forceinline__ void ce_pair_h(hv2& a, hv2& b, bool up) {
  hv2 lo = pkmin(a, b);
  hv2 hi = pkmax(a, b);
  a = sel32(up, lo, hi);
  b = sel32(up, hi, lo);
}

template <int SIZE, int DIST>
__device__ __forceinline__ void stage_x_h(hv2 v[4], int i0) {
  const bool keepmin = (((i0 & DIST) == 0) == ((i0 & SIZE) == 0));
#pragma unroll
  for (int r = 0; r < 4; r++) {
    hv2 pv = i2h(lane_xor_i<(DIST >> 2)>(h2i(v[r])));
    v[r] = sel32(keepmin, pkmin(v[r], pv), pkmax(v[r], pv));
  }
}

template <int SIZE>
__device__ __forceinline__ void stage_d21_h(hv2 v[4], int i0) {
  bool up = ((i0 & SIZE) == 0);
  ce_pair_h(v[0], v[2], up); ce_pair_h(v[1], v[3], up);
  ce_pair_h(v[0], v[1], up); ce_pair_h(v[2], v[3], up);
}

__device__ __forceinline__ void sort256h(hv2 v[4], int lane) {
  int i0 = lane << 2;
  ce_pair_h(v[0], v[1], true); ce_pair_h(v[2], v[3], false);
  stage_d21_h<4>(v, i0);
  stage_x_h<8, 4>(v, i0); stage_d21_h<8>(v, i0);
  stage_x_h<16, 8>(v, i0); stage_x_h<16, 4>(v, i0); stage_d21_h<16>(v, i0);
  stage_x_h<32, 16>(v, i0); stage_x_h<32, 8>(v, i0); stage_x_h<32, 4>(v, i0); stage_d21_h<32>(v, i0);
  stage_x_h<64, 32>(v, i0); stage_x_h<64, 16>(v, i0); stage_x_h<64, 8>(v, i0); stage_x_h<64, 4>(v, i0); stage_d21_h<64>(v, i0);
  stage_x_h<128, 64>(v, i0); stage_x_h<128, 32>(v, i0); stage_x_h<128, 16>(v, i0); stage_x_h<128, 8>(v, i0); stage_x_h<128, 4>(v, i0); stage_d21_h<128>(v, i0);
  stage_x_h<256, 128>(v, i0); stage_x_h<256, 64>(v, i0); stage_x_h<256, 32>(v, i0); stage_x_h<256, 16>(v, i0); stage_x_h<256, 8>(v, i0); stage_x_h<256, 4>(v, i0); stage_d21_h<256>(v, i0);
}

// ---------------- one branch: diff/k3(u,v)/mul/sort/silu/k4 -> out[4] ----------------
template <int DIL>
__device__ __forceinline__ void branch_one(const float* __restrict__ base,
                                           const float* __restrict__ ws,
                                           int g, int w, int lane, float out[4]) {
  float vals[3][3][4];
#pragma unroll
  for (int wi = 0; wi < 3; ++wi) {
    const int wc = w + (wi - 1) * DIL;
    const bool wok = ((unsigned)wc < 256u);
    const float* col = base + (wok ? wc : 0) * 256;
#pragma unroll
    for (int si = 0; si < 3; ++si) {
#pragma unroll
      for (int r = 0; r < 4; ++r) {
        const int h = lane + (r << 6) + (si - 1) * DIL;
        const bool ok = wok && ((unsigned)h < 256u);
        vals[wi][si][r] = ok ? col[h] : 0.0f;
      }
    }
  }
  hv2 uh[4][4], vh[4][4];
#pragma unroll
  for (int r = 0; r < 4; ++r) {
    const float c0 = vals[1][1][r];
    float d0 = c0 - vals[0][0][r];
    float d1 = c0 - vals[1][0][r];
    float d2 = c0 - vals[2][0][r];
    float d3 = c0 - vals[0][1][r];
    float d4 = c0 - vals[2][2][r];
    float d5 = c0 - vals[1][2][r];
    float d6 = c0 - vals[0][2][r];
    float d7 = c0 - vals[2][1][r];
    uh[0][r] = pkrtz(d0 + d4, d0 + d4);
    uh[1][r] = pkrtz(d1 + d5, d1 + d5);
    uh[2][r] = pkrtz(d2 + d6, d2 + d6);
    uh[3][r] = pkrtz(d3 + d7, d3 + d7);
    vh[0][r] = pkrtz(d0 - d4, d0 - d4);
    vh[1][r] = pkrtz(d1 - d5, d1 - d5);
    vh[2][r] = pkrtz(d2 - d6, d2 - d6);
    vh[3][r] = pkrtz(d3 - d7, d3 - d7);
  }
  out[0] = out[1] = out[2] = out[3] = 0.f;
  const uint32_t* k3u = (const uint32_t*)(ws + P_K3U) + g * 32;
  const uint32_t* k3v = (const uint32_t*)(ws + P_K3V) + g * 32;
  const float* k4p = ws + P_K4 + g * 16;
#pragma unroll 1
  for (int p = 0; p < 8; ++p) {
    hv2 t[4];
    hv2 wu[4], wvv[4];
#pragma unroll
    for (int j = 0; j < 4; ++j) {
      wu[j]  = i2h((int)k3u[p * 4 + j]);
      wvv[j] = i2h((int)k3v[p * 4 + j]);
    }
#pragma unroll
    for (int r = 0; r < 4; ++r) {
      hv2 s = pkmul(wu[0], uh[0][r]);
      s = pkfma(wu[1], uh[1][r], s);
      s = pkfma(wu[2], uh[2][r], s);
      s = pkfma(wu[3], uh[3][r], s);
      hv2 d = pkmul(wvv[0], vh[0][r]);
      d = pkfma(wvv[1], vh[1][r], d);
      d = pkfma(wvv[2], vh[2][r], d);
      d = pkfma(wvv[3], vh[3][r], d);
      t[r] = pkmul(s + d, s - d);
    }
    sort256h(t, lane);
    const float k4a = k4p[2 * p], k4b = k4p[2 * p + 1];
#pragma unroll
    for (int r = 0; r < 4; ++r) {
      const float va = (float)t[r].x;
      const float vb = (float)t[r].y;
      out[r] = fmaf(k4a, va * sigmoid_fast(va), out[r]);
      out[r] = fmaf(k4b, vb * sigmoid_fast(vb), out[r]);
    }
  }
}

// ---------------- fused: all 4 dilations, register max/sum, write comb ----------------
__global__ __launch_bounds__(256) void k_branch4(const float* __restrict__ cT,
                                                 const float* __restrict__ ws,
                                                 float* __restrict__ comb) {
  const int tid = threadIdx.x;
  const int lane = tid & 63;
  const int wid = __builtin_amdgcn_readfirstlane(tid >> 6);
  const int wv = (blockIdx.x << 2) + wid;
  const int w = wv & 255;
  const int g = (wv >> 8) & 15;
  const int b = wv >> 12;
  const int boff = (b * 16 + g) << 16;

  float out[4], mx[4], sm[4];
  branch_one<1>(cT + 0 * CTSZ + boff, ws, g, w, lane, out);
#pragma unroll
  for (int r = 0; r < 4; ++r) { mx[r] = out[r]; sm[r] = out[r]; }
  branch_one<3>(cT + 1 * CTSZ + boff, ws, g, w, lane, out);
#pragma unroll
  for (int r = 0; r < 4; ++r) { mx[r] = fmaxf(mx[r], out[r]); sm[r] += out[r]; }
  branch_one<5>(cT + 2 * CTSZ + boff, ws, g, w, lane, out);
#pragma unroll
  for (int r = 0; r < 4; ++r) { mx[r] = fmaxf(mx[r], out[r]); sm[r] += out[r]; }
  branch_one<7>(cT + 3 * CTSZ + boff, ws, g, w, lane, out);
#pragma unroll
  for (int r = 0; r < 4; ++r) { mx[r] = fmaxf(mx[r], out[r]); sm[r] += out[r]; }

  const int obase = (((b * 16 + g) << 8) + w) * 256 + (lane << 2);
  float4 o4;
  o4.x = fmaf(0.25f, sm[0], mx[0]);
  o4.y = fmaf(0.25f, sm[1], mx[1]);
  o4.z = fmaf(0.25f, sm[2], mx[2]);
  o4.w = fmaf(0.25f, sm[3], mx[3]);
  *(float4*)(comb + obase) = o4;
}

// ---------------- sequential fallback: one branch with RMW max/sum ----------------
template <int DIL>
__global__ __launch_bounds__(256) void k_branch(const float* __restrict__ cT,
                                                const float* __restrict__ ws,
                                                float* __restrict__ maxb,
                                                float* __restrict__ sumb,
                                                int initFlag) {
  const int tid = threadIdx.x;
  const int lane = tid & 63;
  const int wid = __builtin_amdgcn_readfirstlane(tid >> 6);
  const int wv = (blockIdx.x << 2) + wid;
  const int w = wv & 255;
  const int g = (wv >> 8) & 15;
  const int b = wv >> 12;

  float out[4];
  branch_one<DIL>(cT + ((b * 16 + g) << 16), ws, g, w, lane, out);

  const int obase = (((b * 16 + g) << 8) + w) * 256 + (lane << 2);
  float4 o4 = make_float4(out[0], out[1], out[2], out[3]);
  float4* mp = (float4*)(maxb + obase);
  float4* sp = (float4*)(sumb + obase);
  if (initFlag) {
    *mp = o4;
    *sp = o4;
  } else {
    float4 m = *mp;
    m.x = fmaxf(m.x, o4.x); m.y = fmaxf(m.y, o4.y);
    m.z = fmaxf(m.z, o4.z); m.w = fmaxf(m.w, o4.w);
    *mp = m;
    float4 s = *sp;
    s.x += o4.x; s.y += o4.y; s.z += o4.z; s.w += o4.w;
    *sp = s;
  }
}

// ---------------- combine + 3x3 conv + BN + SiLU + 1x1 + sigmoid + GATE ----------------
// combMode=1: `a` already holds max+0.25*sum; combMode=0: a=maxb, sb=sumb
__global__ __launch_bounds__(256) void k_tail(const float* __restrict__ a,
                                              const float* __restrict__ sb,
                                              const float* __restrict__ ws,
                                              const float* __restrict__ cen,
                                              const float* __restrict__ mas,
                                              const float* __restrict__ w_out,
                                              const float* __restrict__ b_out,
                                              float* __restrict__ out,
                                              int combMode) {
  __shared__ float lds[16 * 18 * 18];
  __shared__ float ldsf[256];
  int tid = threadIdx.x;
  int b = blockIdx.z;
  int wbase = blockIdx.x * 16, hbase = blockIdx.y * 16;
  const float* mb = a + (b * 16) * HW;
  const float* sbb = sb + (b * 16) * HW;
  for (int i = tid; i < 16 * 18 * 18; i += 256) {
    int g = i / 324; int r = i % 324; int xx = r / 18, yy = r % 18;
    int wq = wbase + xx - 1, hq = hbase + yy - 1;
    float v = 0.0f;
    if (wq >= 0 && wq < 256 && hq >= 0 && hq < 256) {
      int idx = g * HW + wq * 256 + hq;
      v = mb[idx];
      if (!combMode) v += 0.25f * sbb[idx];
    }
    lds[i] = v;
  }
  __syncthreads();
  int xw = tid >> 4, yh = tid & 15;
  float acc[16] = {0.f, 0.f, 0.f, 0.f, 0.f, 0.f, 0.f, 0.f,
                   0.f, 0.f, 0.f, 0.f, 0.f, 0.f, 0.f, 0.f};
  for (int g = 0; g < 16; g++) {
#pragma unroll
    for (int kw = 0; kw < 3; kw++) {
#pragma unroll
      for (int kh = 0; kh < 3; kh++) {
        float v = lds[g * 324 + (xw + kw) * 18 + (yh + kh)];
        const float* wp = ws + P_WRB + ((g * 3 + kw) * 3 + kh) * 16;
#pragma unroll
        for (int co = 0; co < 16; co++) acc[co] = fmaf(wp[co], v, acc[co]);
      }
    }
  }
  float mo = b_out[0];
#pragma unroll
  for (int co = 0; co < 16; co++) {
    float z = acc[co] * ws[P_BNS + co] + ws[P_BNB + co];
    float sl = z * sigmoid_fast(z);
    mo = fmaf(w_out[co], sl, mo);
  }
  float mk = sigmoid_fast(mo);
  ldsf[yh * 16 + xw] = mk;
  __syncthreads();
  {
    int yy = tid >> 4, xx = tid & 15;
    float mkv = ldsf[yy * 16 + xx];
    float m = sigmoid_fast(mas[b * HW + (hbase + yy) * 256 + wbase + xx]);
    float s0 = ws[P_S1], s1 = ws[P_S1 + 1], s2 = ws[P_S1 + 2], s3 = ws[P_S1 + 3];
    float f = mkv * m * s0 + m * s1 + s2 * mkv + s3;
    ldsf[yy * 16 + xx] = f;
  }
  __syncthreads();
  const float* cb = cen + b * 64 * HW;
  float* ob = out + b * 64 * HW;
#pragma unroll 4
  for (int it = 0; it < 16; ++it) {
    int flat = it * 256 + tid;
    int ci = flat >> 6;
    int rr = flat & 63;
    int yy = rr >> 2, wq = rr & 3;
    const float* fr = &ldsf[yy * 16 + wq * 4];
    float4 f4 = make_float4(fr[0], fr[1], fr[2], fr[3]);
    int addr = ci * HW + (hbase + yy) * 256 + wbase + wq * 4;
    const float4 c4 = *(const float4*)(cb + addr);
    float4 o4;
    o4.x = c4.x * f4.x; o4.y = c4.y * f4.y; o4.z = c4.z * f4.z; o4.w = c4.w * f4.w;
    *(float4*)(ob + addr) = o4;
  }
}

extern "C" void kernel_launch(void* const* d_in, const int* in_sizes, int n_in,
                              void* d_out, int out_size, void* d_ws, size_t ws_size,
                              hipStream_t stream) {
  (void)in_sizes; (void)n_in; (void)out_size;
  const float* cen = (const float*)d_in[0];
  const float* mas = (const float*)d_in[1];
  const float* w_in = (const float*)d_in[2];
  const float* b_in = (const float*)d_in[3];
  const float* w_c0 = (const float*)d_in[4];
  const float* b_c0 = (const float*)d_in[5];
  const float* w_c1 = (const float*)d_in[6];
  const float* b_c1 = (const float*)d_in[7];
  const float* w_c2 = (const float*)d_in[8];
  const float* b_c2 = (const float*)d_in[9];
  const float* w_c3 = (const float*)d_in[10];
  const float* b_c3 = (const float*)d_in[11];
  const float* scales1 = (const float*)d_in[12];
  const float* scales2 = (const float*)d_in[13];
  const float* scales3 = (const float*)d_in[14];
  const float* w_base = (const float*)d_in[15];
  const float* bn_gamma = (const float*)d_in[16];
  const float* bn_beta = (const float*)d_in[17];
  const float* bn_mean = (const float*)d_in[18];
  const float* bn_var = (const float*)d_in[19];
  const float* w_out = (const float*)d_in[20];
  const float* b_out = (const float*)d_in[21];
  float* ws = (float*)d_ws;
  float* out = (float*)d_out;

  float* xT = ws + OFF_X;
  float* cT = ws + OFF_CT;

  const size_t needFused = (size_t)(OFF_CT + 4 * CTSZ) * 4;  // 84.0 MB
  const bool fused = ws_size >= needFused;

  k_prep<<<1, 256, 0, stream>>>(w_in, w_c0, w_c1, w_c2, w_c3, w_base, scales1, scales2,
                                scales3, bn_gamma, bn_beta, bn_mean, bn_var, ws);
  k_in<<<dim3(16, 16, 4), 256, 0, stream>>>(cen, b_in, ws, xT);

  if (fused) {
    k_conv<1><<<1024, 256, 0, stream>>>(xT, b_c0, (const uint32_t*)(ws + P_WR0), cT + 0 * CTSZ);
    k_conv<3><<<1024, 256, 0, stream>>>(xT, b_c1, (const uint32_t*)(ws + P_WR1), cT + 1 * CTSZ);
    k_conv<5><<<1024, 256, 0, stream>>>(xT, b_c2, (const uint32_t*)(ws + P_WR2), cT + 2 * CTSZ);
    k_conv<7><<<1024, 256, 0, stream>>>(xT, b_c3, (const uint32_t*)(ws + P_WR3), cT + 3 * CTSZ);
    float* comb = xT;  // xT dead after the 4 convs
    k_branch4<<<4096, 256, 0, stream>>>(cT, ws, comb);
    k_tail<<<dim3(16, 16, 4), 256, 0, stream>>>(comb, comb, ws, cen, mas, w_out, b_out, out, 1);
  } else {
    float* maxb = cT + CTSZ;
    float* sumb = cT + 2 * CTSZ;
    k_conv<1><<<1024, 256, 0, stream>>>(xT, b_c0, (const uint32_t*)(ws + P_WR0), cT);
    k_branch<1><<<4096, 256, 0, stream>>>(cT, ws, maxb, sumb, 1);
    k_conv<3><<<1024, 256, 0, stream>>>(xT, b_c1, (const uint32_t*)(ws + P_WR1), cT);
    k_branch<3><<<4096, 256, 0, stream>>>(cT, ws, maxb, sumb, 0);
    k_conv<5><<<1024, 256, 0, stream>>>(xT, b_c2, (const uint32_t*)(ws + P_WR2), cT);
    k_branch<5><<<4096, 256, 0, stream>>>(cT, ws, maxb, sumb, 0);
    k_conv<7><<<1024, 256, 0, stream>>>(xT, b_c3, (const uint32_t*)(ws + P_WR3), cT);
    k_branch<7><<<4096, 256, 0, stream>>>(cT, ws, maxb, sumb, 0);
    k_tail<<<dim3(16, 16, 4), 256, 0, stream>>>(maxb, sumb, ws, cen, mas, w_out, b_out, out, 0);
  }
}

// Round 16
// 864.998 us; speedup vs baseline: 1.0229x; 1.0170x over previous
//
#include <hip/hip_runtime.h>

#define HW 65536

// ---- ws layout (float offsets) ----
constexpr int OFF_X    = 0;          // xT: 4b*16ci*256w*256h (transposed)
constexpr int OFF_CT   = 4194304;    // c transposed [b][g][w][h]
constexpr int OFF_MAX  = 8388608;
constexpr int OFF_SUM  = 12582912;
constexpr int P_K3  = 17039360;          // 256*8 softmax(scales2)
constexpr int P_K3S = P_K3  + 2048;      // (unused)
constexpr int P_K4  = P_K3S + 2048;      // 16*16 softmax(scales3)
constexpr int P_S1  = P_K4  + 256;       // softmax(scales1), 4
constexpr int P_BNS = P_S1  + 4;         // 16
constexpr int P_BNB = P_BNS + 16;        // 16
constexpr int P_WRI = P_BNB + 16;        // w_in  re-laid [ci][co] 1024
// conv weights packed fp16 co-pairs (uint32)
constexpr int P_WR0 = P_WRI + 1024;      // 128 u32  (1x1)
constexpr int P_WR1 = P_WR0 + 256;       // 1152 u32 (3x3)
constexpr int P_WR2 = P_WR1 + 2304;      // 3200 u32 (5x5)
constexpr int P_WR3 = P_WR2 + 6400;      // 6272 u32 (7x7)
constexpr int P_WRB = P_WR3 + 12544;     // 2304 fp32 (tail 3x3)
constexpr int P_K3U = P_WRB + 2304;      // packed fp16 (k3[j]+k3[j+4])/2: 512 u32
constexpr int P_K3V = P_K3U + 512;       // packed fp16 (k3[j]-k3[j+4])/2: 512 u32

// clang-native packed fp16
typedef _Float16 hv2 __attribute__((ext_vector_type(2)));

__device__ __forceinline__ int h2i(hv2 v) { return __builtin_bit_cast(int, v); }
__device__ __forceinline__ hv2 i2h(int v) { return __builtin_bit_cast(hv2, v); }

__device__ __forceinline__ hv2 pkrtz(float a, float b) {
  return __builtin_bit_cast(hv2, __builtin_amdgcn_cvt_pkrtz(a, b));
}

__device__ __forceinline__ hv2 pk_fma_n(hv2 a, hv2 b, hv2 c) {
#if __has_builtin(__builtin_elementwise_fma)
  return __builtin_elementwise_fma(a, b, c);
#else
  return a * b + c;
#endif
}

__device__ __forceinline__ hv2 pkmin(hv2 a, hv2 b) {
  hv2 d; asm("v_pk_min_f16 %0, %1, %2" : "=v"(d) : "v"(a), "v"(b)); return d;
}
__device__ __forceinline__ hv2 pkmax(hv2 a, hv2 b) {
  hv2 d; asm("v_pk_max_f16 %0, %1, %2" : "=v"(d) : "v"(a), "v"(b)); return d;
}
__device__ __forceinline__ hv2 pkmul(hv2 a, hv2 b) {
  hv2 d; asm("v_pk_mul_f16 %0, %1, %2" : "=v"(d) : "v"(a), "v"(b)); return d;
}
__device__ __forceinline__ hv2 pkfma(hv2 a, hv2 b, hv2 c) {
  hv2 d; asm("v_pk_fma_f16 %0, %1, %2, %3" : "=v"(d) : "v"(a), "v"(b), "v"(c)); return d;
}

__device__ __forceinline__ hv2 sel32(bool c, hv2 a, hv2 b) {
  return i2h(c ? h2i(a) : h2i(b));
}

// cross-lane xor: ds_swizzle (DS pipe, free when VALU-bound) for <32, shfl for 32
template <int LMASK>
__device__ __forceinline__ int lane_xor_i(int x) {
  if constexpr (LMASK < 32) {
    return __builtin_amdgcn_ds_swizzle(x, (LMASK << 10) | 0x1F);
  } else {
    return __shfl_xor(x, LMASK, 64);
  }
}

__device__ __forceinline__ float sigmoid_fast(float x) {
  return __fdividef(1.0f, 1.0f + __expf(-x));
}

// ---------------- prep ----------------
__global__ void k_prep(const float* __restrict__ w_in, const float* __restrict__ w_c0,
                       const float* __restrict__ w_c1, const float* __restrict__ w_c2,
                       const float* __restrict__ w_c3, const float* __restrict__ w_base,
                       const float* __restrict__ scales1, const float* __restrict__ scales2,
                       const float* __restrict__ scales3, const float* __restrict__ bn_gamma,
                       const float* __restrict__ bn_beta, const float* __restrict__ bn_mean,
                       const float* __restrict__ bn_var, float* __restrict__ ws) {
  int tid = threadIdx.x;  // 256
  {
    const float* srow = scales2 + tid * 8;
    float v[8]; float mx = -1e30f;
    for (int j = 0; j < 8; j++) { v[j] = srow[j]; mx = fmaxf(mx, v[j]); }
    float s = 0.f;
    for (int j = 0; j < 8; j++) { v[j] = __expf(v[j] - mx); s += v[j]; }
    float inv = 1.0f / s;
    for (int j = 0; j < 8; j++) ws[P_K3 + tid * 8 + j] = v[j] * inv;
  }
  if (tid < 16) {
    const float* srow = scales3 + tid * 16;
    float v[16]; float mx = -1e30f;
    for (int e = 0; e < 16; e++) { v[e] = srow[e]; mx = fmaxf(mx, v[e]); }
    float s = 0.f;
    for (int e = 0; e < 16; e++) { v[e] = __expf(v[e] - mx); s += v[e]; }
    float inv = 1.0f / s;
    for (int e = 0; e < 16; e++) ws[P_K4 + tid * 16 + e] = v[e] * inv;
  }
  if (tid == 0) {
    float v[4]; float mx = -1e30f;
    for (int i = 0; i < 4; i++) { v[i] = scales1[i]; mx = fmaxf(mx, v[i]); }
    float s = 0.f;
    for (int i = 0; i < 4; i++) { v[i] = __expf(v[i] - mx); s += v[i]; }
    for (int i = 0; i < 4; i++) ws[P_S1 + i] = v[i] / s;
  }
  if (tid < 16) {
    float rs = rsqrtf(bn_var[tid] + 1e-5f);
    float sc = bn_gamma[tid] * rs;
    ws[P_BNS + tid] = sc;
    ws[P_BNB + tid] = bn_beta[tid] - bn_mean[tid] * sc;
  }
  for (int i = tid; i < 1024; i += 256) { int ci = i >> 4, co = i & 15; ws[P_WRI + i] = w_in[co * 64 + ci]; }
  // packed fp16 co-pair conv weights
  {
    uint32_t* w0 = (uint32_t*)(ws + P_WR0);
    for (int i = tid; i < 128; i += 256) {
      int cp = i & 7, ci = i >> 3;
      hv2 wv;
      wv.x = (_Float16)w_c0[(2 * cp) * 16 + ci];
      wv.y = (_Float16)w_c0[(2 * cp + 1) * 16 + ci];
      w0[ci * 8 + cp] = __builtin_bit_cast(uint32_t, wv);
    }
    uint32_t* w1 = (uint32_t*)(ws + P_WR1);
    for (int i = tid; i < 1152; i += 256) {
      int cp = i & 7; int r = i >> 3; int kw = r % 3; r /= 3; int kh = r % 3; int ci = r / 3;
      hv2 wv;
      wv.x = (_Float16)w_c1[((2 * cp) * 16 + ci) * 9 + kh * 3 + kw];
      wv.y = (_Float16)w_c1[((2 * cp + 1) * 16 + ci) * 9 + kh * 3 + kw];
      w1[((ci * 3 + kh) * 3 + kw) * 8 + cp] = __builtin_bit_cast(uint32_t, wv);
    }
    uint32_t* w2 = (uint32_t*)(ws + P_WR2);
    for (int i = tid; i < 3200; i += 256) {
      int cp = i & 7; int r = i >> 3; int kw = r % 5; r /= 5; int kh = r % 5; int ci = r / 5;
      hv2 wv;
      wv.x = (_Float16)w_c2[((2 * cp) * 16 + ci) * 25 + kh * 5 + kw];
      wv.y = (_Float16)w_c2[((2 * cp + 1) * 16 + ci) * 25 + kh * 5 + kw];
      w2[((ci * 5 + kh) * 5 + kw) * 8 + cp] = __builtin_bit_cast(uint32_t, wv);
    }
    uint32_t* w3 = (uint32_t*)(ws + P_WR3);
    for (int i = tid; i < 6272; i += 256) {
      int cp = i & 7; int r = i >> 3; int kw = r % 7; r /= 7; int kh = r % 7; int ci = r / 7;
      hv2 wv;
      wv.x = (_Float16)w_c3[((2 * cp) * 16 + ci) * 49 + kh * 7 + kw];
      wv.y = (_Float16)w_c3[((2 * cp + 1) * 16 + ci) * 49 + kh * 7 + kw];
      w3[((ci * 7 + kh) * 7 + kw) * 8 + cp] = __builtin_bit_cast(uint32_t, wv);
    }
  }
  // wbr[((g*3+kw)*3+kh)*16+co] = w_base[co][g][kh][kw]  (fp32, tail conv)
  for (int i = tid; i < 2304; i += 256) {
    int co = i & 15; int r = i >> 4; int kh = r % 3; r /= 3; int kw = r % 3; int g = r / 3;
    ws[P_WRB + i] = w_base[((co * 16 + g) * 3 + kh) * 3 + kw];
  }
  __syncthreads();
  // factored k3 weights: k3u = (k3[j]+k3[j+4])/2, k3v = (k3[j]-k3[j+4])/2, j=0..3
  uint32_t* k3u = (uint32_t*)(ws + P_K3U);
  uint32_t* k3v = (uint32_t*)(ws + P_K3V);
  for (int i = tid; i < 512; i += 256) {
    int g = i >> 5, p = (i >> 2) & 7, j = i & 3;
    const float* r0 = ws + P_K3 + g * 128 + (2 * p) * 8;
    const float* r1 = ws + P_K3 + g * 128 + (2 * p + 1) * 8;
    hv2 wu, wv;
    wu.x = (_Float16)((r0[j] + r0[j + 4]) * 0.5f);
    wu.y = (_Float16)((r1[j] + r1[j + 4]) * 0.5f);
    wv.x = (_Float16)((r0[j] - r0[j + 4]) * 0.5f);
    wv.y = (_Float16)((r1[j] - r1[j + 4]) * 0.5f);
    k3u[i] = __builtin_bit_cast(uint32_t, wu);
    k3v[i] = __builtin_bit_cast(uint32_t, wv);
  }
}

// ---------------- 1x1 conv 64->16, writes TRANSPOSED xT[b][ci][w][h] ----------------
__global__ __launch_bounds__(256) void k_in(const float* __restrict__ cen,
                                            const float* __restrict__ b_in,
                                            const float* __restrict__ ws,
                                            float* __restrict__ xT) {
  __shared__ float ldst[16 * 16 * 17];  // [co][tx(w)][ty(h)] padded
  int tid = threadIdx.x;
  int b = blockIdx.z;
  int hbase = blockIdx.y * 16, wbase = blockIdx.x * 16;
  int ty = tid >> 4, tx = tid & 15;  // h, w within tile
  const float* wri = ws + P_WRI;
  float acc[16];
#pragma unroll
  for (int co = 0; co < 16; co++) acc[co] = b_in[co];
  const float* cp = cen + b * 64 * HW + (hbase + ty) * 256 + wbase + tx;
#pragma unroll 4
  for (int ci = 0; ci < 64; ci++) {
    float v = cp[ci * HW];
#pragma unroll
    for (int co = 0; co < 16; co++) acc[co] = fmaf(wri[ci * 16 + co], v, acc[co]);
  }
#pragma unroll
  for (int co = 0; co < 16; co++) ldst[(co * 16 + tx) * 17 + ty] = acc[co];
  __syncthreads();
  int wy = tid >> 4, hx = tid & 15;  // w, h for transposed write
#pragma unroll
  for (int ci = 0; ci < 16; ci++) {
    xT[((b * 16 + ci) << 16) + (wbase + wy) * 256 + hbase + hx] =
        ldst[(ci * 16 + wy) * 17 + hx];
  }
}

// ---------------- branch conv: direct per-kh offset loads (no shuffles, no DS) ----------------
template <int KS, bool SAFE>
__device__ __forceinline__ void conv_body(const float* __restrict__ xb,
                                          const uint32_t* __restrict__ wrh,
                                          int w, int hbase, int lane, hv2 acc[8]) {
  constexpr int P = KS / 2;
#pragma unroll 2
  for (int ci = 0; ci < 16; ci++) {
#pragma unroll
    for (int kw = 0; kw < KS; kw++) {
      const int wc = w + kw - P;
      if (KS > 1 && (unsigned)wc >= 256u) continue;  // zero-pad: wave-uniform skip
      const float* col = xb + (ci << 16) + (wc << 8);
      const int hb = hbase + lane - P;
#pragma unroll
      for (int kh = 0; kh < KS; kh++) {
        float tv;
        if constexpr (SAFE) {
          tv = col[hb + kh];
        } else {
          const int h = hb + kh;
          tv = ((unsigned)h < 256u) ? col[h] : 0.0f;
        }
        const hv2 tp = pkrtz(tv, tv);
        const uint32_t* wp = wrh + ((ci * KS + kh) * KS + kw) * 8;
#pragma unroll
        for (int cp = 0; cp < 8; cp++)
          acc[cp] = pk_fma_n(i2h((int)wp[cp]), tp, acc[cp]);
      }
    }
  }
}

template <int KS>
__global__ __launch_bounds__(256) void k_conv(const float* __restrict__ xT,
                                              const float* __restrict__ bias,
                                              const uint32_t* __restrict__ wrh,
                                              float* __restrict__ cT) {
  const int tid = threadIdx.x;
  const int lane = tid & 63;
  const int wv = (blockIdx.x << 2) + (tid >> 6);  // 4096 waves: b(4) x w(256) x hseg(4)
  const int hseg = wv & 3;
  const int w = (wv >> 2) & 255;
  const int b = wv >> 10;
  const int hbase = hseg << 6;
  const float* xb = xT + ((b * 16) << 16);

  hv2 acc[8];
#pragma unroll
  for (int cp = 0; cp < 8; cp++) {
    hv2 bv;
    bv.x = (_Float16)bias[2 * cp];
    bv.y = (_Float16)bias[2 * cp + 1];
    acc[cp] = bv;
  }

  if (KS == 1 || (hseg != 0 && hseg != 3)) {
    conv_body<KS, true>(xb, wrh, w, hbase, lane, acc);
  } else {
    conv_body<KS, false>(xb, wrh, w, hbase, lane, acc);
  }

  float* o = cT + ((b * 16) << 16) + (w << 8) + hbase + lane;
#pragma unroll
  for (int cp = 0; cp < 8; cp++) {
    o[(2 * cp) << 16] = (float)acc[cp].x;
    o[(2 * cp + 1) << 16] = (float)acc[cp].y;
  }
}

// ---------------- packed-fp16 bitonic sort of 256 values: 64 lanes x 4 regs ----------------
__device__ __forceinline__ void ce_pair_h(hv2& a, hv2& b, bool up) {
  hv2 lo = pkmin(a, b);
  hv2 hi = pkmax(a, b);
  a = sel32(up, lo, hi);
  b = sel32(up, hi, lo);
}

template <int SIZE, int DIST>
__device__ __forceinline__ void stage_x_h(hv2 v[4], int i0) {
  const bool keepmin = (((i0 & DIST) == 0) == ((i0 & SIZE) == 0));
#pragma unroll
  for (int r = 0; r < 4; r++) {
    hv2 pv = i2h(lane_xor_i<(DIST >> 2)>(h2i(v[r])));
    v[r] = sel32(keepmin, pkmin(v[r], pv), pkmax(v[r], pv));
  }
}

template <int SIZE>
__device__ __forceinline__ void stage_d21_h(hv2 v[4], int i0) {
  bool up = ((i0 & SIZE) == 0);
  ce_pair_h(v[0], v[2], up); ce_pair_h(v[1], v[3], up);
  ce_pair_h(v[0], v[1], up); ce_pair_h(v[2], v[3], up);
}

__device__ __forceinline__ void sort256h(hv2 v[4], int lane) {
  int i0 = lane << 2;
  ce_pair_h(v[0], v[1], true); ce_pair_h(v[2], v[3], false);   // size 2
  stage_d21_h<4>(v, i0);                                       // size 4
  stage_x_h<8, 4>(v, i0); stage_d21_h<8>(v, i0);
  stage_x_h<16, 8>(v, i0); stage_x_h<16, 4>(v, i0); stage_d21_h<16>(v, i0);
  stage_x_h<32, 16>(v, i0); stage_x_h<32, 8>(v, i0); stage_x_h<32, 4>(v, i0); stage_d21_h<32>(v, i0);
  stage_x_h<64, 32>(v, i0); stage_x_h<64, 16>(v, i0); stage_x_h<64, 8>(v, i0); stage_x_h<64, 4>(v, i0); stage_d21_h<64>(v, i0);
  stage_x_h<128, 64>(v, i0); stage_x_h<128, 32>(v, i0); stage_x_h<128, 16>(v, i0); stage_x_h<128, 8>(v, i0); stage_x_h<128, 4>(v, i0); stage_d21_h<128>(v, i0);
  stage_x_h<256, 128>(v, i0); stage_x_h<256, 64>(v, i0); stage_x_h<256, 32>(v, i0); stage_x_h<256, 16>(v, i0); stage_x_h<256, 8>(v, i0); stage_x_h<256, 4>(v, i0); stage_d21_h<256>(v, i0);
}

// ---------------- fused diff/k3/mul/sort/silu/k4 + branch max/sum accum ----------------
template <int DIL>
__global__ __launch_bounds__(256) void k_branch(const float* __restrict__ cT,
                                                const float* __restrict__ ws,
                                                float* __restrict__ maxb,
                                                float* __restrict__ sumb,
                                                int initFlag) {
  const int tid = threadIdx.x;
  const int lane = tid & 63;
  // wave-uniform task id via readfirstlane -> scalar addressing + s_load weights
  const int wid = __builtin_amdgcn_readfirstlane(tid >> 6);
  const int wv = (blockIdx.x << 2) + wid;
  const int w = wv & 255;
  const int g = (wv >> 8) & 15;
  const int b = wv >> 12;
  const float* base = cT + ((b * 16 + g) << 16);

  float vals[3][3][4];
#pragma unroll
  for (int wi = 0; wi < 3; ++wi) {
    const int wc = w + (wi - 1) * DIL;
    const bool wok = ((unsigned)wc < 256u);
    const float* col = base + (wok ? wc : 0) * 256;
#pragma unroll
    for (int si = 0; si < 3; ++si) {
#pragma unroll
      for (int r = 0; r < 4; ++r) {
        const int h = lane + (r << 6) + (si - 1) * DIL;
        const bool ok = wok && ((unsigned)h < 256u);
        vals[wi][si][r] = ok ? col[h] : 0.0f;
      }
    }
  }
  // directional differences -> u/v sum-difference pairs (fp32), pack to fp16x2
  hv2 uh[4][4], vh[4][4];
#pragma unroll
  for (int r = 0; r < 4; ++r) {
    const float c0 = vals[1][1][r];
    float d0 = c0 - vals[0][0][r];
    float d1 = c0 - vals[1][0][r];
    float d2 = c0 - vals[2][0][r];
    float d3 = c0 - vals[0][1][r];
    float d4 = c0 - vals[2][2][r];
    float d5 = c0 - vals[1][2][r];
    float d6 = c0 - vals[0][2][r];
    float d7 = c0 - vals[2][1][r];
    uh[0][r] = pkrtz(d0 + d4, d0 + d4);
    uh[1][r] = pkrtz(d1 + d5, d1 + d5);
    uh[2][r] = pkrtz(d2 + d6, d2 + d6);
    uh[3][r] = pkrtz(d3 + d7, d3 + d7);
    vh[0][r] = pkrtz(d0 - d4, d0 - d4);
    vh[1][r] = pkrtz(d1 - d5, d1 - d5);
    vh[2][r] = pkrtz(d2 - d6, d2 - d6);
    vh[3][r] = pkrtz(d3 - d7, d3 - d7);
  }
  float out[4] = {0.f, 0.f, 0.f, 0.f};
  const uint32_t* k3u = (const uint32_t*)(ws + P_K3U) + g * 32;
  const uint32_t* k3v = (const uint32_t*)(ws + P_K3V) + g * 32;
  const float* k4p = ws + P_K4 + g * 16;
#pragma unroll 1
  for (int p = 0; p < 8; ++p) {
    hv2 t[4];
    hv2 wu[4], wvv[4];
#pragma unroll
    for (int j = 0; j < 4; ++j) {
      wu[j]  = i2h((int)k3u[p * 4 + j]);
      wvv[j] = i2h((int)k3v[p * 4 + j]);
    }
#pragma unroll
    for (int r = 0; r < 4; ++r) {
      hv2 s = pkmul(wu[0], uh[0][r]);
      s = pkfma(wu[1], uh[1][r], s);
      s = pkfma(wu[2], uh[2][r], s);
      s = pkfma(wu[3], uh[3][r], s);
      hv2 d = pkmul(wvv[0], vh[0][r]);
      d = pkfma(wvv[1], vh[1][r], d);
      d = pkfma(wvv[2], vh[2][r], d);
      d = pkfma(wvv[3], vh[3][r], d);
      t[r] = pkmul(s + d, s - d);  // o1*o2 exactly
    }
    sort256h(t, lane);
    const float k4a = k4p[2 * p], k4b = k4p[2 * p + 1];
#pragma unroll
    for (int r = 0; r < 4; ++r) {
      const float va = (float)t[r].x;
      const float vb = (float)t[r].y;
      out[r] = fmaf(k4a, va * sigmoid_fast(va), out[r]);
      out[r] = fmaf(k4b, vb * sigmoid_fast(vb), out[r]);
    }
  }
  const int obase = (((b * 16 + g) << 8) + w) * 256 + (lane << 2);
  float4 o4 = make_float4(out[0], out[1], out[2], out[3]);
  float4* mp = (float4*)(maxb + obase);
  float4* sp = (float4*)(sumb + obase);
  if (initFlag) {
    *mp = o4;
    *sp = o4;
  } else {
    float4 m = *mp;
    m.x = fmaxf(m.x, o4.x); m.y = fmaxf(m.y, o4.y);
    m.z = fmaxf(m.z, o4.z); m.w = fmaxf(m.w, o4.w);
    *mp = m;
    float4 s = *sp;
    s.x += o4.x; s.y += o4.y; s.z += o4.z; s.w += o4.w;
    *sp = s;
  }
}

// ---------------- combine + 3x3 conv + BN + SiLU + 1x1 + sigmoid + GATE (fused tail) ----------------
__global__ __launch_bounds__(256) void k_tail(const float* __restrict__ maxb,
                                              const float* __restrict__ sumb,
                                              const float* __restrict__ ws,
                                              const float* __restrict__ cen,
                                              const float* __restrict__ mas,
                                              const float* __restrict__ w_out,
                                              const float* __restrict__ b_out,
                                              float* __restrict__ out) {
  __shared__ float lds[16 * 18 * 18];
  __shared__ float ldsf[256];
  int tid = threadIdx.x;
  int b = blockIdx.z;
  int wbase = blockIdx.x * 16, hbase = blockIdx.y * 16;
  const float* mb = maxb + (b * 16) * HW;  // [g][w][h]
  const float* sb = sumb + (b * 16) * HW;
  for (int i = tid; i < 16 * 18 * 18; i += 256) {
    int g = i / 324; int r = i % 324; int xx = r / 18, yy = r % 18;
    int wq = wbase + xx - 1, hq = hbase + yy - 1;
    float v = 0.0f;
    if (wq >= 0 && wq < 256 && hq >= 0 && hq < 256) {
      int idx = g * HW + wq * 256 + hq;
      v = mb[idx] + 0.25f * sb[idx];
    }
    lds[i] = v;
  }
  __syncthreads();
  int xw = tid >> 4, yh = tid & 15;  // pixel (w = wbase+xw, h = hbase+yh)
  float acc[16] = {0.f, 0.f, 0.f, 0.f, 0.f, 0.f, 0.f, 0.f,
                   0.f, 0.f, 0.f, 0.f, 0.f, 0.f, 0.f, 0.f};
  for (int g = 0; g < 16; g++) {
#pragma unroll
    for (int kw = 0; kw < 3; kw++) {
#pragma unroll
      for (int kh = 0; kh < 3; kh++) {
        float v = lds[g * 324 + (xw + kw) * 18 + (yh + kh)];
        const float* wp = ws + P_WRB + ((g * 3 + kw) * 3 + kh) * 16;
#pragma unroll
        for (int co = 0; co < 16; co++) acc[co] = fmaf(wp[co], v, acc[co]);
      }
    }
  }
  float mo = b_out[0];
#pragma unroll
  for (int co = 0; co < 16; co++) {
    float z = acc[co] * ws[P_BNS + co] + ws[P_BNB + co];
    float sl = z * sigmoid_fast(z);
    mo = fmaf(w_out[co], sl, mo);
  }
  float mk = sigmoid_fast(mo);
  ldsf[yh * 16 + xw] = mk;
  __syncthreads();
  // compute gate factor f per pixel under coalesced (yy,xx) mapping
  {
    int yy = tid >> 4, xx = tid & 15;
    float mkv = ldsf[yy * 16 + xx];
    float m = sigmoid_fast(mas[b * HW + (hbase + yy) * 256 + wbase + xx]);
    float s0 = ws[P_S1], s1 = ws[P_S1 + 1], s2 = ws[P_S1 + 2], s3 = ws[P_S1 + 3];
    float f = mkv * m * s0 + m * s1 + s2 * mkv + s3;
    ldsf[yy * 16 + xx] = f;  // each thread overwrites the slot it just read
  }
  __syncthreads();
  // gate all 64 cen channels, float4 over w
  const float* cb = cen + b * 64 * HW;
  float* ob = out + b * 64 * HW;
#pragma unroll 4
  for (int it = 0; it < 16; ++it) {
    int flat = it * 256 + tid;
    int ci = flat >> 6;
    int rr = flat & 63;
    int yy = rr >> 2, wq = rr & 3;
    const float* fr = &ldsf[yy * 16 + wq * 4];
    float4 f4 = make_float4(fr[0], fr[1], fr[2], fr[3]);
    int addr = ci * HW + (hbase + yy) * 256 + wbase + wq * 4;
    const float4 c4 = *(const float4*)(cb + addr);
    float4 o4;
    o4.x = c4.x * f4.x; o4.y = c4.y * f4.y; o4.z = c4.z * f4.z; o4.w = c4.w * f4.w;
    *(float4*)(ob + addr) = o4;
  }
}

extern "C" void kernel_launch(void* const* d_in, const int* in_sizes, int n_in,
                              void* d_out, int out_size, void* d_ws, size_t ws_size,
                              hipStream_t stream) {
  (void)in_sizes; (void)n_in; (void)out_size; (void)ws_size;
  const float* cen = (const float*)d_in[0];
  const float* mas = (const float*)d_in[1];
  const float* w_in = (const float*)d_in[2];
  const float* b_in = (const float*)d_in[3];
  const float* w_c0 = (const float*)d_in[4];
  const float* b_c0 = (const float*)d_in[5];
  const float* w_c1 = (const float*)d_in[6];
  const float* b_c1 = (const float*)d_in[7];
  const float* w_c2 = (const float*)d_in[8];
  const float* b_c2 = (const float*)d_in[9];
  const float* w_c3 = (const float*)d_in[10];
  const float* b_c3 = (const float*)d_in[11];
  const float* scales1 = (const float*)d_in[12];
  const float* scales2 = (const float*)d_in[13];
  const float* scales3 = (const float*)d_in[14];
  const float* w_base = (const float*)d_in[15];
  const float* bn_gamma = (const float*)d_in[16];
  const float* bn_beta = (const float*)d_in[17];
  const float* bn_mean = (const float*)d_in[18];
  const float* bn_var = (const float*)d_in[19];
  const float* w_out = (const float*)d_in[20];
  const float* b_out = (const float*)d_in[21];
  float* ws = (float*)d_ws;
  float* out = (float*)d_out;

  float* xT = ws + OFF_X;
  float* cT = ws + OFF_CT;
  float* maxb = ws + OFF_MAX;
  float* sumb = ws + OFF_SUM;

  k_prep<<<1, 256, 0, stream>>>(w_in, w_c0, w_c1, w_c2, w_c3, w_base, scales1, scales2,
                                scales3, bn_gamma, bn_beta, bn_mean, bn_var, ws);
  k_in<<<dim3(16, 16, 4), 256, 0, stream>>>(cen, b_in, ws, xT);

  k_conv<1><<<1024, 256, 0, stream>>>(xT, b_c0, (const uint32_t*)(ws + P_WR0), cT);
  k_branch<1><<<4096, 256, 0, stream>>>(cT, ws, maxb, sumb, 1);
  k_conv<3><<<1024, 256, 0, stream>>>(xT, b_c1, (const uint32_t*)(ws + P_WR1), cT);
  k_branch<3><<<4096, 256, 0, stream>>>(cT, ws, maxb, sumb, 0);
  k_conv<5><<<1024, 256, 0, stream>>>(xT, b_c2, (const uint32_t*)(ws + P_WR2), cT);
  k_branch<5><<<4096, 256, 0, stream>>>(cT, ws, maxb, sumb, 0);
  k_conv<7><<<1024, 256, 0, stream>>>(xT, b_c3, (const uint32_t*)(ws + P_WR3), cT);
  k_branch<7><<<4096, 256, 0, stream>>>(cT, ws, maxb, sumb, 0);

  k_tail<<<dim3(16, 16, 4), 256, 0, stream>>>(maxb, sumb, ws, cen, mas, w_out, b_out, out);
}